// Round 18
// baseline (266.271 us; speedup 1.0000x reference)
//
#include <hip/hip_runtime.h>
#include <hip/hip_bf16.h>
#include <math.h>

#define NN 8192
#define HD 128
#define NB 2
#define EPSF 1e-6f
#define BM 64
#define BKE 256               // bf16 K elements per step (tile = 64x256x2B = 32 KB)
#define NSTEP (NN / BKE)      // 32

typedef __attribute__((ext_vector_type(8))) __bf16 bf16x8;
typedef __attribute__((ext_vector_type(4))) __bf16 bf16x4;
typedef __attribute__((ext_vector_type(4))) float f32x4;

// ---- Kernel 1: norm = rsqrt(sum|adj_row|+eps)  AND  adjh = bf16(adj) --------
// R10-verified. Streams 537 MB fp32 in, 268 MB bf16 out. The bf16 image ~fits
// the 256 MB Infinity Cache, so the gemm's A-read is L3-served.
__global__ __launch_bounds__(256) void k_degcast(const float* __restrict__ adj,
                                                 float* __restrict__ norm,
                                                 __hip_bfloat16* __restrict__ adjh) {
    const int row  = blockIdx.x * 4 + (threadIdx.x >> 6);
    const int lane = threadIdx.x & 63;
    const float4* p = (const float4*)(adj + (size_t)row * NN);
    bf16x4* q = (bf16x4*)(adjh + (size_t)row * NN);
    float s = 0.f;
#pragma unroll
    for (int i = 0; i < 16; ++i) {
        float4 a = p[i * 128 + lane];
        float4 b = p[i * 128 + 64 + lane];
        s += fabsf(a.x) + fabsf(a.y) + fabsf(a.z) + fabsf(a.w)
           + fabsf(b.x) + fabsf(b.y) + fabsf(b.z) + fabsf(b.w);
        bf16x4 ha, hb;
        ha[0] = (__bf16)a.x; ha[1] = (__bf16)a.y; ha[2] = (__bf16)a.z; ha[3] = (__bf16)a.w;
        hb[0] = (__bf16)b.x; hb[1] = (__bf16)b.y; hb[2] = (__bf16)b.z; hb[3] = (__bf16)b.w;
        q[i * 128 + lane]      = ha;
        q[i * 128 + 64 + lane] = hb;
    }
#pragma unroll
    for (int off = 32; off > 0; off >>= 1) s += __shfl_down(s, off);
    if (lane == 0) norm[row] = rsqrtf(s + EPSF);
}

// --- Kernel 2: snT2[b][n/32][h][n&31] = bf16( (x@W)[b][n][h] * norm[b][n] ) --
// K-panel-major layout (R15-verified): gemm B loads are 1 KB/wave contiguous.
__global__ __launch_bounds__(256) void k_support(const float* __restrict__ x,
                                                 const float* __restrict__ W,
                                                 const float* __restrict__ norm,
                                                 __hip_bfloat16* __restrict__ snT2) {
    const int b  = blockIdx.x >> 9;
    const int n0 = (blockIdx.x & 511) * 16;
    __shared__ float xs[16][132];
    const int t = threadIdx.x;
    {
        const int r = t >> 4, c0 = (t & 15) * 8;
        const float* src = x + ((size_t)(b * NN + n0 + r)) * HD + c0;
        *(float4*)&xs[r][c0]     = *(const float4*)src;
        *(float4*)&xs[r][c0 + 4] = *(const float4*)(src + 4);
    }
    __syncthreads();
    const int nl = t & 15;
    const int h0 = (t >> 4) * 8;
    float s[8] = {0.f,0.f,0.f,0.f,0.f,0.f,0.f,0.f};
#pragma unroll 4
    for (int k = 0; k < HD; ++k) {
        const float xv = xs[nl][k];
        const float* wr = W + k * HD + h0;
        float4 wa = *(const float4*)wr;
        float4 wb = *(const float4*)(wr + 4);
        s[0] += xv * wa.x; s[1] += xv * wa.y; s[2] += xv * wa.z; s[3] += xv * wa.w;
        s[4] += xv * wb.x; s[5] += xv * wb.y; s[6] += xv * wb.z; s[7] += xv * wb.w;
    }
    const int n  = n0 + nl;
    const float nv = norm[b * NN + n];
    __hip_bfloat16* dst = snT2 + (size_t)b * NN * HD
                        + (size_t)(n >> 5) * (HD * 32) + (n & 31);
#pragma unroll
    for (int hb = 0; hb < 8; ++hb)
        dst[(h0 + hb) * 32] = __float2bfloat16(s[hb] * nv);
}

// async global->LDS, 16 B per lane (dest = wave-uniform base + lane*16)
__device__ __forceinline__ void gload_lds16(const void* g, void* l) {
    __builtin_amdgcn_global_load_lds(
        (const __attribute__((address_space(1))) void*)g,
        (__attribute__((address_space(3))) void*)l, 16, 0, 0);
}

// ---- Kernel 3: out = elu( norm_m * (adjh[b] @ support_norm^T) + bias ) ------
// R17's verified BM=64 counted-vmcnt structure with bf16 A (BK=256): staged
// bytes per K halved, no in-loop cvt (LDS feeds bf16x8 fragments directly),
// LDS read bytes halved. Row geometry unchanged (512 B rows = 32 granules,
// both-sides XOR ^(row&7)); fragment granule = (ks*4+g)^xr (R10-verified
// read pattern). Per half-iter: B(k+1)[16] + stage(k+2)[4] -> at WAITN the
// 24 newest = st(k+1)4 + B(k+1)16 + st(k+2)4, so WAITN(24) retires st(k)
// and B(k). 4 x 32 KB buffers = 2-barrier overwrite distance.
__global__ __launch_bounds__(512, 1) void k_gemm18(const __hip_bfloat16* __restrict__ adjh,
                                                   const __hip_bfloat16* __restrict__ snT2,
                                                   const float* __restrict__ norm,
                                                   const float* __restrict__ bias,
                                                   float* __restrict__ out) {
    const int b    = blockIdx.y;
    const int swz  = (blockIdx.x & 7) * 16 + (blockIdx.x >> 3);   // XCD-bijective (128 = 8x16)
    const int m0   = swz * BM;
    const int w    = threadIdx.x >> 6;     // 0..7
    const int mh   = w & 1;                // m-half owner (32 rows)
    const int hs   = w >> 1;               // h-slice owner (32 h)
    const int lane = threadIdx.x & 63;
    const int fr   = lane & 15;
    const int g    = lane >> 4;
    const int xr   = fr & 7;

    const __hip_bfloat16* adjB = adjh + (size_t)b * NN * NN;
    const __hip_bfloat16* snB  = snT2 + (size_t)b * NN * HD;

    __shared__ __align__(16) char Abuf[4][BM * BKE * 2];   // 4 x 32 KB

    // staging: thread call c covers 16B-granule fg = c*512 + w*64 + lane
    // (2048 granules = 64 rows x 32); row = fg>>5, slot = (fg&31)^(row&7).
    const __hip_bfloat16* sptr[4];
#pragma unroll
    for (int c = 0; c < 4; ++c) {
        const int fg   = c * 512 + w * 64 + lane;
        const int row  = fg >> 5;
        const int slot = (fg & 31) ^ (row & 7);
        sptr[c] = adjB + (size_t)(m0 + row) * NN + slot * 8;
    }

    // B base: panel-major; lane chunk = (hs*32 + ht*16 + fr)*32 + g*8
    const __hip_bfloat16* bp0 = snB + (size_t)(hs * 32 + fr) * 32 + g * 8;
    const __hip_bfloat16* bp1 = bp0 + 16 * 32;

    f32x4 acc[2][2] = {};   // [m-tile within half][h-tile]
    bf16x8 BfA[2][8], BfB[2][8];   // [h-tile][ks]; 2 banks

#define STAGE(idx) do {                                                       \
        char* nb_ = Abuf[(idx) & 3];                                          \
        _Pragma("unroll")                                                     \
        for (int c = 0; c < 4; ++c)                                           \
            gload_lds16(sptr[c] + (size_t)(idx) * BKE, &nb_[c * 8192 + w * 1024]); \
    } while (0)
#define LOADB(BX, idx) do {                                                   \
        _Pragma("unroll")                                                     \
        for (int ks = 0; ks < 8; ++ks) {                                      \
            const size_t kp_ = (size_t)((idx) * 8 + ks) * (HD * 32);          \
            BX[0][ks] = *(const bf16x8*)(bp0 + kp_);                          \
            BX[1][ks] = *(const bf16x8*)(bp1 + kp_);                          \
        }                                                                     \
    } while (0)
#define WAITN(n) asm volatile("s_waitcnt vmcnt(" #n ")" ::: "memory")
#define BAR() do { __builtin_amdgcn_s_barrier();                              \
                   __builtin_amdgcn_sched_barrier(0); } while (0)
#define COMPUTE(kidx, BX) do {                                                \
        const char* lb_ = Abuf[(kidx) & 3];                                   \
        _Pragma("unroll")                                                     \
        for (int mt = 0; mt < 2; ++mt) {                                      \
            const char* rbase_ = lb_ + (mh * 32 + mt * 16 + fr) * 512;        \
            _Pragma("unroll")                                                 \
            for (int ks = 0; ks < 8; ++ks) {                                  \
                bf16x8 af_ = *(const bf16x8*)(rbase_ + (((ks * 4 + g) ^ xr) << 4)); \
                acc[mt][0] = __builtin_amdgcn_mfma_f32_16x16x32_bf16(af_, BX[0][ks], acc[mt][0], 0, 0, 0); \
                acc[mt][1] = __builtin_amdgcn_mfma_f32_16x16x32_bf16(af_, BX[1][ks], acc[mt][1], 0, 0, 0); \
            }                                                                 \
        }                                                                     \
    } while (0)

    // ---- prologue: stage 0,1; B(0) into bank A ----
    STAGE(0);
    STAGE(1);
    LOADB(BfA, 0);

    // ---- main loop ----
#pragma unroll 1
    for (int k = 0; k < NSTEP - 3; k += 2) {
        LOADB(BfB, k + 1);
        STAGE(k + 2);
        WAITN(24); BAR();
        COMPUTE(k, BfA);

        LOADB(BfA, k + 2);
        STAGE(k + 3);
        WAITN(24); BAR();
        COMPUTE(k + 1, BfB);
    }

    // ---- tail ----
    LOADB(BfB, NSTEP - 1);
    WAITN(0); BAR();
    COMPUTE(NSTEP - 2, BfA);

    WAITN(0); BAR();
    COMPUTE(NSTEP - 1, BfB);

#undef STAGE
#undef LOADB
#undef WAITN
#undef BAR
#undef COMPUTE

    // ---- fused epilogue: *norm_m + bias, elu ----
    const float* normB = norm + b * NN + m0;
    float* outB = out + ((size_t)b * NN + m0) * HD;
#pragma unroll
    for (int mt = 0; mt < 2; ++mt)
#pragma unroll
        for (int ht = 0; ht < 2; ++ht) {
            const int h  = hs * 32 + ht * 16 + fr;
            const float bv = bias[h];
#pragma unroll
            for (int j = 0; j < 4; ++j) {
                const int r = mh * 32 + mt * 16 + g * 4 + j;
                float v = acc[mt][ht][j] * normB[r] + bv;
                v = v > 0.f ? v : expm1f(v);
                outB[(size_t)r * HD + h] = v;
            }
        }
}

extern "C" void kernel_launch(void* const* d_in, const int* in_sizes, int n_in,
                              void* d_out, int out_size, void* d_ws, size_t ws_size,
                              hipStream_t stream) {
    (void)in_sizes; (void)n_in; (void)out_size; (void)ws_size;
    const float* x    = (const float*)d_in[0];
    const float* adj  = (const float*)d_in[1];
    const float* W    = (const float*)d_in[2];
    const float* bias = (const float*)d_in[3];
    float* out = (float*)d_out;

    float* norm = (float*)d_ws;                                     // 64 KB
    __hip_bfloat16* snT2 = (__hip_bfloat16*)((char*)d_ws + 65536);  // 4 MB, panel-major
    __hip_bfloat16* adjh = (__hip_bfloat16*)((char*)d_ws + 65536 + (4 << 20)); // 268 MB

    k_degcast<<<dim3(NB * NN / 4),  dim3(256), 0, stream>>>(adj, norm, adjh);
    k_support<<<dim3(NB * NN / 16), dim3(256), 0, stream>>>(x, W, norm, snT2);
    k_gemm18 <<<dim3(NN / BM, NB),  dim3(512), 0, stream>>>(adjh, snT2, norm, bias, out);
}

// Round 19
// 259.141 us; speedup vs baseline: 1.0275x; 1.0275x over previous
//
#include <hip/hip_runtime.h>
#include <hip/hip_bf16.h>
#include <math.h>

#define NN 8192
#define HD 128
#define NB 2
#define EPSF 1e-6f
#define BM 64
#define BK 64                 // fp32 K elements per step (tile = 64x64x4B = 16 KB)
#define KSPL 2
#define KCH (NN / KSPL)       // 4096
#define NSTEP (KCH / BK)      // 64

typedef __attribute__((ext_vector_type(8))) __bf16 bf16x8;
typedef __attribute__((ext_vector_type(4))) float f32x4;

// ---------------- Kernel 1: norm = rsqrt(sum|adj_row| + eps) -----------------
__global__ __launch_bounds__(256) void k_degree(const float* __restrict__ adj,
                                                float* __restrict__ norm) {
    const int row  = blockIdx.x * 4 + (threadIdx.x >> 6);
    const int lane = threadIdx.x & 63;
    const float4* p = (const float4*)(adj + (size_t)row * NN);
    float s = 0.f;
#pragma unroll
    for (int i = 0; i < 32; ++i) {
        float4 v = p[(size_t)i * 64 + lane];
        s += fabsf(v.x) + fabsf(v.y) + fabsf(v.z) + fabsf(v.w);
    }
#pragma unroll
    for (int off = 32; off > 0; off >>= 1) s += __shfl_down(s, off);
    if (lane == 0) norm[row] = rsqrtf(s + EPSF);
}

// --- Kernel 2: snT2[b][n/32][h][n&31] = bf16( (x@W)[b][n][h] * norm[b][n] ) --
// K-panel-major layout (R15-verified): gemm B loads are 1 KB/wave contiguous.
__global__ __launch_bounds__(256) void k_support(const float* __restrict__ x,
                                                 const float* __restrict__ W,
                                                 const float* __restrict__ norm,
                                                 __hip_bfloat16* __restrict__ snT2) {
    const int b  = blockIdx.x >> 9;
    const int n0 = (blockIdx.x & 511) * 16;
    __shared__ float xs[16][132];
    const int t = threadIdx.x;
    {
        const int r = t >> 4, c0 = (t & 15) * 8;
        const float* src = x + ((size_t)(b * NN + n0 + r)) * HD + c0;
        *(float4*)&xs[r][c0]     = *(const float4*)src;
        *(float4*)&xs[r][c0 + 4] = *(const float4*)(src + 4);
    }
    __syncthreads();
    const int nl = t & 15;
    const int h0 = (t >> 4) * 8;
    float s[8] = {0.f,0.f,0.f,0.f,0.f,0.f,0.f,0.f};
#pragma unroll 4
    for (int k = 0; k < HD; ++k) {
        const float xv = xs[nl][k];
        const float* wr = W + k * HD + h0;
        float4 wa = *(const float4*)wr;
        float4 wb = *(const float4*)(wr + 4);
        s[0] += xv * wa.x; s[1] += xv * wa.y; s[2] += xv * wa.z; s[3] += xv * wa.w;
        s[4] += xv * wb.x; s[5] += xv * wb.y; s[6] += xv * wb.z; s[7] += xv * wb.w;
    }
    const int n  = n0 + nl;
    const float nv = norm[b * NN + n];
    __hip_bfloat16* dst = snT2 + (size_t)b * NN * HD
                        + (size_t)(n >> 5) * (HD * 32) + (n & 31);
#pragma unroll
    for (int hb = 0; hb < 8; ++hb)
        dst[(h0 + hb) * 32] = __float2bfloat16(s[hb] * nv);
}

__device__ __forceinline__ bf16x8 cvt8(float4 a, float4 b) {
    bf16x8 r;
    r[0] = (__bf16)a.x; r[1] = (__bf16)a.y; r[2] = (__bf16)a.z; r[3] = (__bf16)a.w;
    r[4] = (__bf16)b.x; r[5] = (__bf16)b.y; r[6] = (__bf16)b.z; r[7] = (__bf16)b.w;
    return r;
}

// async global->LDS, 16 B per lane (dest = wave-uniform base + lane*16)
__device__ __forceinline__ void gload_lds16(const float* g, void* l) {
    __builtin_amdgcn_global_load_lds(
        (const __attribute__((address_space(1))) void*)g,
        (__attribute__((address_space(3))) void*)l, 16, 0, 0);
}

// ---- Kernel 3: partial[b][mb][ksp] = adj[b][mb-rows][ksp-halfK] @ snT2^T ----
// R17's counted-vmcnt structure, K-split 2 so the grid supplies 512 blocks =
// 2 resident/CU (the never-cleanly-tested lever: partner block covers barrier
// convergence and delivery hiccups). A traffic unchanged (each block reads
// its own half-rows), B traffic unchanged (half the panels x same h). BK=64
// fp32 -> 16 KB tile, 4 buffers = 64 KB LDS. Per half-iter: B(k+1)[4] +
// stage(k+2)[2] -> WAITN(8) retires st(k) (newest 8 = st(k+1)2+B(k+1)4+
// st(k+2)2; B RAW is compiler-guarded). Raw partial sums to ws; k_fin fuses
// the split-reduce + norm/bias/elu epilogue.
__global__ __launch_bounds__(512, 4) void k_gemm19(const float* __restrict__ adj,
                                                   const __hip_bfloat16* __restrict__ snT2,
                                                   float* __restrict__ partials) {
    const int b    = blockIdx.y;
    const int swz  = (blockIdx.x & 7) * 32 + (blockIdx.x >> 3);   // XCD-bijective (256 = 8x32)
    const int mb   = swz >> 1;             // m-block (64 rows)
    const int ksp  = swz & 1;              // K half owner
    const int m0   = mb * BM;
    const int kb   = ksp * KCH;
    const int w    = threadIdx.x >> 6;     // 0..7
    const int mh   = w & 1;                // m-half owner (32 rows)
    const int hs   = w >> 1;               // h-slice owner (32 h)
    const int lane = threadIdx.x & 63;
    const int fr   = lane & 15;
    const int g    = lane >> 4;
    const int xr   = fr & 7;

    const float* adjB = adj + (size_t)b * NN * NN;
    const __hip_bfloat16* snB = snT2 + (size_t)b * NN * HD;

    __shared__ __align__(16) char Abuf[4][BM * BK * 4];   // 4 x 16 KB

    // staging: 1024 granules of 16 B (64 rows x 16); thread call c covers
    // fg = c*512 + w*64 + lane; row = fg>>4, slot = (fg&15)^(row&7).
    const float* sptr[2];
#pragma unroll
    for (int c = 0; c < 2; ++c) {
        const int fg   = c * 512 + w * 64 + lane;
        const int row  = fg >> 4;
        const int slot = (fg & 15) ^ (row & 7);
        sptr[c] = adjB + (size_t)(m0 + row) * NN + kb + slot * 4;
    }

    // B base: panel-major; panel index base = ksp*128; step idx adds idx*2+ks2.
    const __hip_bfloat16* bp0 = snB + (size_t)ksp * 128 * (HD * 32)
                              + (size_t)(hs * 32 + fr) * 32 + g * 8;
    const __hip_bfloat16* bp1 = bp0 + 16 * 32;

    f32x4 acc[2][2] = {};          // [m-tile within half][h-tile]
    bf16x8 BfA[2][2], BfB[2][2];   // [h-tile][ks2]; 2 banks

#define STAGE(idx) do {                                                       \
        char* nb_ = Abuf[(idx) & 3];                                          \
        _Pragma("unroll")                                                     \
        for (int c = 0; c < 2; ++c)                                           \
            gload_lds16(sptr[c] + (size_t)(idx) * BK, &nb_[c * 8192 + w * 1024]); \
    } while (0)
#define LOADB(BX, idx) do {                                                   \
        _Pragma("unroll")                                                     \
        for (int ks = 0; ks < 2; ++ks) {                                      \
            const size_t kp_ = (size_t)((idx) * 2 + ks) * (HD * 32);          \
            BX[0][ks] = *(const bf16x8*)(bp0 + kp_);                          \
            BX[1][ks] = *(const bf16x8*)(bp1 + kp_);                          \
        }                                                                     \
    } while (0)
#define WAITN(n) asm volatile("s_waitcnt vmcnt(" #n ")" ::: "memory")
#define BAR() do { __builtin_amdgcn_s_barrier();                              \
                   __builtin_amdgcn_sched_barrier(0); } while (0)
#define COMPUTE(kidx, BX) do {                                                \
        const char* lb_ = Abuf[(kidx) & 3];                                   \
        _Pragma("unroll")                                                     \
        for (int mt = 0; mt < 2; ++mt) {                                      \
            const char* rbase_ = lb_ + (mh * 32 + mt * 16 + fr) * 256;        \
            _Pragma("unroll")                                                 \
            for (int ks = 0; ks < 2; ++ks) {                                  \
                float4 fa_ = *(const float4*)(rbase_ + ((ks * 8 + ((g * 2 + 0) ^ xr)) << 4)); \
                float4 fb_ = *(const float4*)(rbase_ + ((ks * 8 + ((g * 2 + 1) ^ xr)) << 4)); \
                bf16x8 af_ = cvt8(fa_, fb_);                                  \
                acc[mt][0] = __builtin_amdgcn_mfma_f32_16x16x32_bf16(af_, BX[0][ks], acc[mt][0], 0, 0, 0); \
                acc[mt][1] = __builtin_amdgcn_mfma_f32_16x16x32_bf16(af_, BX[1][ks], acc[mt][1], 0, 0, 0); \
            }                                                                 \
        }                                                                     \
    } while (0)

    // ---- prologue: stage 0,1; B(0) into bank A ----
    STAGE(0);
    STAGE(1);
    LOADB(BfA, 0);

    // ---- main loop ----
#pragma unroll 1
    for (int k = 0; k < NSTEP - 3; k += 2) {
        LOADB(BfB, k + 1);
        STAGE(k + 2);
        WAITN(8); BAR();
        COMPUTE(k, BfA);

        LOADB(BfA, k + 2);
        STAGE(k + 3);
        WAITN(8); BAR();
        COMPUTE(k + 1, BfB);
    }

    // ---- tail ----
    LOADB(BfB, NSTEP - 1);
    WAITN(0); BAR();
    COMPUTE(NSTEP - 2, BfA);

    WAITN(0); BAR();
    COMPUTE(NSTEP - 1, BfB);

#undef STAGE
#undef LOADB
#undef WAITN
#undef BAR
#undef COMPUTE

    // ---- write raw partial tile (64x128 f32) ----
    float* pb = partials + ((((size_t)b * 128 + mb) * 2 + ksp) << 13);  // 8192 f32
#pragma unroll
    for (int mt = 0; mt < 2; ++mt)
#pragma unroll
        for (int ht = 0; ht < 2; ++ht) {
            const int h = hs * 32 + ht * 16 + fr;
#pragma unroll
            for (int j = 0; j < 4; ++j) {
                const int r = mh * 32 + mt * 16 + g * 4 + j;
                pb[r * 128 + h] = acc[mt][ht][j];
            }
        }
}

// ---- Kernel 4: out = elu( norm_m * (p0 + p1) + bias ) ----------------------
__global__ __launch_bounds__(256) void k_fin(const float* __restrict__ partials,
                                             const float* __restrict__ norm,
                                             const float* __restrict__ bias,
                                             float* __restrict__ out) {
    const int f = blockIdx.x * 256 + threadIdx.x;
    const size_t e = (size_t)f * 4;
    const int b   = (int)(e >> 20);              // 8192*128 = 2^20
    const int rem = (int)(e & 1048575);
    const int m   = rem >> 7;
    const int h   = rem & 127;
    const int mb  = m >> 6;
    const int r   = m & 63;
    const size_t base = (((size_t)b * 128 + mb) * 2) << 13;
    const int off = r * 128 + h;
    float4 p0 = *(const float4*)(partials + base + off);
    float4 p1 = *(const float4*)(partials + base + 8192 + off);
    const float nm = norm[b * NN + m];
    float4 bv = *(const float4*)(bias + h);
    float4 o;
    o.x = (p0.x + p1.x) * nm + bv.x;
    o.y = (p0.y + p1.y) * nm + bv.y;
    o.z = (p0.z + p1.z) * nm + bv.z;
    o.w = (p0.w + p1.w) * nm + bv.w;
    o.x = o.x > 0.f ? o.x : expm1f(o.x);
    o.y = o.y > 0.f ? o.y : expm1f(o.y);
    o.z = o.z > 0.f ? o.z : expm1f(o.z);
    o.w = o.w > 0.f ? o.w : expm1f(o.w);
    *(float4*)(out + e) = o;
}

extern "C" void kernel_launch(void* const* d_in, const int* in_sizes, int n_in,
                              void* d_out, int out_size, void* d_ws, size_t ws_size,
                              hipStream_t stream) {
    (void)in_sizes; (void)n_in; (void)out_size; (void)ws_size;
    const float* x    = (const float*)d_in[0];
    const float* adj  = (const float*)d_in[1];
    const float* W    = (const float*)d_in[2];
    const float* bias = (const float*)d_in[3];
    float* out = (float*)d_out;

    float* norm = (float*)d_ws;                                     // 64 KB
    __hip_bfloat16* snT2 = (__hip_bfloat16*)((char*)d_ws + 65536);  // 4 MB, panel-major
    float* partials = (float*)((char*)d_ws + 65536 + (4 << 20));    // 16 MB

    k_degree <<<dim3(NB * NN / 4),  dim3(256), 0, stream>>>(adj, norm);
    k_support<<<dim3(NB * NN / 16), dim3(256), 0, stream>>>(x, W, norm, snT2);
    k_gemm19 <<<dim3(256, NB),      dim3(512), 0, stream>>>(adj, snT2, partials);
    k_fin    <<<dim3(2048),         dim3(256), 0, stream>>>(partials, norm, bias, out);
}